// Round 1
// baseline (1479.376 us; speedup 1.0000x reference)
//
#include <hip/hip_runtime.h>
#include <hip/hip_bf16.h>
#include <math.h>

// Problem constants (fixed by setup_inputs)
#define B_  2
#define S_  2048
#define D_  1024
#define H_  16
#define HD_ 64
#define NE_ 3072   // 3*D
#define M_  4096   // B*S

// ---------------------------------------------------------------------------
// GEMM core: C[m][n] = sum_k A[m][k] * W[n][k]   (A row-major MxK, W row-major NxK)
// 64x64 tile, 16x16 threads, 4x4 per thread, TILE_K=16, K-major LDS (stride 68).
// ---------------------------------------------------------------------------

// QKV projection with scatter epilogue into q/k/v buffers laid out [B,H,S,HD]
__global__ __launch_bounds__(256) void gemm_qkv(const float* __restrict__ X,
                                                const float* __restrict__ W,
                                                float* __restrict__ q,
                                                float* __restrict__ k,
                                                float* __restrict__ v) {
    __shared__ __align__(16) float AsT[16][68];
    __shared__ __align__(16) float BsT[16][68];
    const int tx = threadIdx.x, ty = threadIdx.y;
    const int t  = ty * 16 + tx;
    const int m0 = blockIdx.y * 64;
    const int n0 = blockIdx.x * 64;
    const int ml = t >> 2;           // 0..63
    const int kq = (t & 3) << 2;     // 0,4,8,12
    float acc[4][4] = {};
    for (int k0 = 0; k0 < D_; k0 += 16) {
        __syncthreads();
        float4 a4 = *(const float4*)(X + (size_t)(m0 + ml) * D_ + k0 + kq);
        AsT[kq+0][ml] = a4.x; AsT[kq+1][ml] = a4.y; AsT[kq+2][ml] = a4.z; AsT[kq+3][ml] = a4.w;
        float4 b4 = *(const float4*)(W + (size_t)(n0 + ml) * D_ + k0 + kq);
        BsT[kq+0][ml] = b4.x; BsT[kq+1][ml] = b4.y; BsT[kq+2][ml] = b4.z; BsT[kq+3][ml] = b4.w;
        __syncthreads();
        #pragma unroll
        for (int kk = 0; kk < 16; ++kk) {
            float4 av = *(const float4*)&AsT[kk][ty * 4];
            float4 bv = *(const float4*)&BsT[kk][tx * 4];
            float aa[4] = {av.x, av.y, av.z, av.w};
            float bb[4] = {bv.x, bv.y, bv.z, bv.w};
            #pragma unroll
            for (int i = 0; i < 4; ++i)
                #pragma unroll
                for (int j = 0; j < 4; ++j) acc[i][j] = fmaf(aa[i], bb[j], acc[i][j]);
        }
    }
    // scatter epilogue: n = n0 + tx*4 + j decomposes as (c, h, d); tile spans one (c,h)
    const int c = n0 >> 10;
    const int h = (n0 >> 6) & 15;
    float* dst = (c == 0) ? q : (c == 1) ? k : v;
    #pragma unroll
    for (int i = 0; i < 4; ++i) {
        int m = m0 + ty * 4 + i;
        int b = m >> 11, s = m & (S_ - 1);
        float4 o4 = make_float4(acc[i][0], acc[i][1], acc[i][2], acc[i][3]);
        *(float4*)(dst + ((size_t)((b * H_ + h) * S_ + s)) * HD_ + tx * 4) = o4;
    }
}

// Output projection: out[m][n] = sum_d att[m][d] * Wo[n][d]
__global__ __launch_bounds__(256) void gemm_out(const float* __restrict__ A,
                                                const float* __restrict__ W,
                                                float* __restrict__ C) {
    __shared__ __align__(16) float AsT[16][68];
    __shared__ __align__(16) float BsT[16][68];
    const int tx = threadIdx.x, ty = threadIdx.y;
    const int t  = ty * 16 + tx;
    const int m0 = blockIdx.y * 64;
    const int n0 = blockIdx.x * 64;
    const int ml = t >> 2;
    const int kq = (t & 3) << 2;
    float acc[4][4] = {};
    for (int k0 = 0; k0 < D_; k0 += 16) {
        __syncthreads();
        float4 a4 = *(const float4*)(A + (size_t)(m0 + ml) * D_ + k0 + kq);
        AsT[kq+0][ml] = a4.x; AsT[kq+1][ml] = a4.y; AsT[kq+2][ml] = a4.z; AsT[kq+3][ml] = a4.w;
        float4 b4 = *(const float4*)(W + (size_t)(n0 + ml) * D_ + k0 + kq);
        BsT[kq+0][ml] = b4.x; BsT[kq+1][ml] = b4.y; BsT[kq+2][ml] = b4.z; BsT[kq+3][ml] = b4.w;
        __syncthreads();
        #pragma unroll
        for (int kk = 0; kk < 16; ++kk) {
            float4 av = *(const float4*)&AsT[kk][ty * 4];
            float4 bv = *(const float4*)&BsT[kk][tx * 4];
            float aa[4] = {av.x, av.y, av.z, av.w};
            float bb[4] = {bv.x, bv.y, bv.z, bv.w};
            #pragma unroll
            for (int i = 0; i < 4; ++i)
                #pragma unroll
                for (int j = 0; j < 4; ++j) acc[i][j] = fmaf(aa[i], bb[j], acc[i][j]);
        }
    }
    #pragma unroll
    for (int i = 0; i < 4; ++i) {
        float4 o4 = make_float4(acc[i][0], acc[i][1], acc[i][2], acc[i][3]);
        *(float4*)(C + (size_t)(m0 + ty * 4 + i) * D_ + n0 + tx * 4) = o4;
    }
}

// ---------------------------------------------------------------------------
// RoPE applied in-place on q and k ([B,H,S,HD] layout). token_positions == s.
// ---------------------------------------------------------------------------
__global__ __launch_bounds__(256) void rope_qk(float* __restrict__ q, float* __restrict__ k) {
    int g = blockIdx.x * 256 + threadIdx.x;      // 0 .. 2*B*H*S*32-1
    int which = g >> 21;                          // B*H*S*32 = 2^21
    int rem   = g & ((1 << 21) - 1);
    int tt = rem & 31;
    int s  = (rem >> 5) & (S_ - 1);
    int bh = rem >> 16;                           // S*32 = 2^16
    float* buf = which ? k : q;
    size_t base = ((size_t)bh * S_ + s) * HD_ + 2 * tt;
    float x1 = buf[base], x2 = buf[base + 1];
    // inv_freq = 10000^(-t/32) = 2^(-t * log2(10000)/32)
    float inv = exp2f(-(float)tt * (13.287712379549449f / 32.0f));
    float fr  = (float)s * inv;
    float sn, cs;
    sincosf(fr, &sn, &cs);
    buf[base]     = x1 * cs - x2 * sn;
    buf[base + 1] = x1 * sn + x2 * cs;
}

// ---------------------------------------------------------------------------
// Causal flash attention: block = 4 waves x 64 lanes, 16 queries per block
// (4 per wave). Lane l owns key j0+l for QK^T, dim l for PV. Online softmax.
// ---------------------------------------------------------------------------
__global__ __launch_bounds__(256) void attn(const float* __restrict__ qb,
                                            const float* __restrict__ kb,
                                            const float* __restrict__ vb,
                                            float* __restrict__ att) {
    __shared__ float Kl[64][65];
    __shared__ float Vl[64][65];
    __shared__ float ql[16][65];
    __shared__ float pl[4][4][64];
    const int bx = blockIdx.x;
    const int bh = bx >> 7;            // / (S/16)
    const int qt = bx & 127;
    const int qbase = qt * 16;
    const int t  = threadIdx.x;
    const int w  = t >> 6;
    const int ln = t & 63;
    const int b = bh >> 4, h = bh & 15;
    const float* qg = qb + (size_t)bh * S_ * HD_;
    const float* kg = kb + (size_t)bh * S_ * HD_;
    const float* vg = vb + (size_t)bh * S_ * HD_;
    {   // stage q tile, pre-scaled by 1/sqrt(hd)
        int r  = t >> 4;
        int d4 = (t & 15) * 4;
        float4 v4 = *(const float4*)(qg + (size_t)(qbase + r) * HD_ + d4);
        ql[r][d4+0] = v4.x * 0.125f; ql[r][d4+1] = v4.y * 0.125f;
        ql[r][d4+2] = v4.z * 0.125f; ql[r][d4+3] = v4.w * 0.125f;
    }
    float m_[4], l_[4], O_[4];
    #pragma unroll
    for (int i = 0; i < 4; ++i) { m_[i] = -1e30f; l_[i] = 0.f; O_[i] = 0.f; }
    const int qr0 = w * 4;
    const int ntiles = (qbase + 15) / 64 + 1;
    for (int jt = 0; jt < ntiles; ++jt) {
        const int j0 = jt * 64;
        __syncthreads();
        {   // stage K,V tile (64 keys x 64 dims)
            int r  = t >> 2;
            int c0 = (t & 3) * 16;
            const float* krow = kg + (size_t)(j0 + r) * HD_ + c0;
            const float* vrow = vg + (size_t)(j0 + r) * HD_ + c0;
            #pragma unroll
            for (int u = 0; u < 16; u += 4) {
                float4 kv = *(const float4*)(krow + u);
                Kl[r][c0+u] = kv.x; Kl[r][c0+u+1] = kv.y; Kl[r][c0+u+2] = kv.z; Kl[r][c0+u+3] = kv.w;
                float4 vv = *(const float4*)(vrow + u);
                Vl[r][c0+u] = vv.x; Vl[r][c0+u+1] = vv.y; Vl[r][c0+u+2] = vv.z; Vl[r][c0+u+3] = vv.w;
            }
        }
        __syncthreads();
        // scores: lane ln <-> key j0+ln, 4 queries share each K read
        float sc[4] = {0.f, 0.f, 0.f, 0.f};
        for (int d = 0; d < 64; ++d) {
            float kd = Kl[ln][d];
            sc[0] = fmaf(ql[qr0+0][d], kd, sc[0]);
            sc[1] = fmaf(ql[qr0+1][d], kd, sc[1]);
            sc[2] = fmaf(ql[qr0+2][d], kd, sc[2]);
            sc[3] = fmaf(ql[qr0+3][d], kd, sc[3]);
        }
        const int j = j0 + ln;
        float alpha[4];
        #pragma unroll
        for (int qi = 0; qi < 4; ++qi) {
            const int qglob = qbase + qr0 + qi;
            float s_ = (j <= qglob) ? sc[qi] : -1e30f;
            float tm = s_;
            #pragma unroll
            for (int off = 32; off; off >>= 1) tm = fmaxf(tm, __shfl_xor(tm, off, 64));
            float mn = fmaxf(m_[qi], tm);
            float p  = __expf(s_ - mn);      // masked lanes underflow to 0
            float ts = p;
            #pragma unroll
            for (int off = 32; off; off >>= 1) ts += __shfl_xor(ts, off, 64);
            alpha[qi] = __expf(m_[qi] - mn); // first tile: exp(-1e30-mn)=0 zeroes stale state
            l_[qi] = l_[qi] * alpha[qi] + ts;
            m_[qi] = mn;
            pl[w][qi][ln] = p;
        }
        __syncthreads();   // publish pl (uniform control flow: all waves reach this)
        float o0 = O_[0] * alpha[0], o1 = O_[1] * alpha[1];
        float o2 = O_[2] * alpha[2], o3 = O_[3] * alpha[3];
        for (int jj = 0; jj < 64; ++jj) {
            float vd = Vl[jj][ln];
            o0 = fmaf(pl[w][0][jj], vd, o0);
            o1 = fmaf(pl[w][1][jj], vd, o1);
            o2 = fmaf(pl[w][2][jj], vd, o2);
            o3 = fmaf(pl[w][3][jj], vd, o3);
        }
        O_[0] = o0; O_[1] = o1; O_[2] = o2; O_[3] = o3;
    }
    // write att in [B,S,H*HD] row-major so the O-projection GEMM reads it contiguously
    #pragma unroll
    for (int qi = 0; qi < 4; ++qi) {
        int s = qbase + qr0 + qi;
        att[((size_t)(b * S_ + s)) * D_ + h * HD_ + ln] = O_[qi] / l_[qi];
    }
}

// ---------------------------------------------------------------------------
extern "C" void kernel_launch(void* const* d_in, const int* in_sizes, int n_in,
                              void* d_out, int out_size, void* d_ws, size_t ws_size,
                              hipStream_t stream) {
    const float* X    = (const float*)d_in[0];   // [B,S,D] fp32
    const float* Wqkv = (const float*)d_in[2];   // [3D,D] fp32
    const float* Wo   = (const float*)d_in[3];   // [D,D] fp32
    float* out = (float*)d_out;

    float* ws = (float*)d_ws;
    const size_t QS = (size_t)B_ * H_ * S_ * HD_;   // 4,194,304 floats
    float* q   = ws;
    float* k   = ws + QS;
    float* v   = ws + 2 * QS;
    float* att = ws + 3 * QS;                        // total 64 MiB fp32

    dim3 blk(16, 16);
    gemm_qkv<<<dim3(NE_ / 64, M_ / 64), blk, 0, stream>>>(X, Wqkv, q, k, v);
    rope_qk<<<(unsigned)(QS / 256), 256, 0, stream>>>(q, k);   // 2*B*H*S*32 threads
    attn<<<B_ * H_ * (S_ / 16), 256, 0, stream>>>(q, k, v, att);
    gemm_out<<<dim3(D_ / 64, M_ / 64), blk, 0, stream>>>(att, Wo, out);
}

// Round 2
// 681.457 us; speedup vs baseline: 2.1709x; 2.1709x over previous
//
#include <hip/hip_runtime.h>
#include <hip/hip_bf16.h>
#include <math.h>

// Problem constants (fixed by setup_inputs)
#define B_  2
#define S_  2048
#define D_  1024
#define H_  16
#define HD_ 64
#define NE_ 3072   // 3*D
#define M_  4096   // B*S

typedef __attribute__((ext_vector_type(8))) short bf16x8;
typedef __attribute__((ext_vector_type(4))) float f32x4;

__device__ __forceinline__ short f2bf(float f) {
    union { float f; unsigned u; } v; v.f = f;
    unsigned u = v.u;
    u += 0x7fffu + ((u >> 16) & 1u);   // round-to-nearest-even
    return (short)(u >> 16);
}

// ---------------------------------------------------------------------------
// GEMM core: C[m][n] = sum_k A[m][k] * W[n][k]   (A row-major MxK, W row-major NxK)
// 64x64 tile, 16x16 threads, 4x4 per thread, TILE_K=16, K-major LDS (stride 68).
// ---------------------------------------------------------------------------

// QKV projection with scatter epilogue into q/k/v buffers laid out [B,H,S,HD]
__global__ __launch_bounds__(256) void gemm_qkv(const float* __restrict__ X,
                                                const float* __restrict__ W,
                                                float* __restrict__ q,
                                                float* __restrict__ k,
                                                float* __restrict__ v) {
    __shared__ __align__(16) float AsT[16][68];
    __shared__ __align__(16) float BsT[16][68];
    const int tx = threadIdx.x, ty = threadIdx.y;
    const int t  = ty * 16 + tx;
    const int m0 = blockIdx.y * 64;
    const int n0 = blockIdx.x * 64;
    const int ml = t >> 2;           // 0..63
    const int kq = (t & 3) << 2;     // 0,4,8,12
    float acc[4][4] = {};
    for (int k0 = 0; k0 < D_; k0 += 16) {
        __syncthreads();
        float4 a4 = *(const float4*)(X + (size_t)(m0 + ml) * D_ + k0 + kq);
        AsT[kq+0][ml] = a4.x; AsT[kq+1][ml] = a4.y; AsT[kq+2][ml] = a4.z; AsT[kq+3][ml] = a4.w;
        float4 b4 = *(const float4*)(W + (size_t)(n0 + ml) * D_ + k0 + kq);
        BsT[kq+0][ml] = b4.x; BsT[kq+1][ml] = b4.y; BsT[kq+2][ml] = b4.z; BsT[kq+3][ml] = b4.w;
        __syncthreads();
        #pragma unroll
        for (int kk = 0; kk < 16; ++kk) {
            float4 av = *(const float4*)&AsT[kk][ty * 4];
            float4 bv = *(const float4*)&BsT[kk][tx * 4];
            float aa[4] = {av.x, av.y, av.z, av.w};
            float bb[4] = {bv.x, bv.y, bv.z, bv.w};
            #pragma unroll
            for (int i = 0; i < 4; ++i)
                #pragma unroll
                for (int j = 0; j < 4; ++j) acc[i][j] = fmaf(aa[i], bb[j], acc[i][j]);
        }
    }
    const int c = n0 >> 10;
    const int h = (n0 >> 6) & 15;
    float* dst = (c == 0) ? q : (c == 1) ? k : v;
    #pragma unroll
    for (int i = 0; i < 4; ++i) {
        int m = m0 + ty * 4 + i;
        int b = m >> 11, s = m & (S_ - 1);
        float4 o4 = make_float4(acc[i][0], acc[i][1], acc[i][2], acc[i][3]);
        *(float4*)(dst + ((size_t)((b * H_ + h) * S_ + s)) * HD_ + tx * 4) = o4;
    }
}

// Output projection: out[m][n] = sum_d att[m][d] * Wo[n][d]
__global__ __launch_bounds__(256) void gemm_out(const float* __restrict__ A,
                                                const float* __restrict__ W,
                                                float* __restrict__ C) {
    __shared__ __align__(16) float AsT[16][68];
    __shared__ __align__(16) float BsT[16][68];
    const int tx = threadIdx.x, ty = threadIdx.y;
    const int t  = ty * 16 + tx;
    const int m0 = blockIdx.y * 64;
    const int n0 = blockIdx.x * 64;
    const int ml = t >> 2;
    const int kq = (t & 3) << 2;
    float acc[4][4] = {};
    for (int k0 = 0; k0 < D_; k0 += 16) {
        __syncthreads();
        float4 a4 = *(const float4*)(A + (size_t)(m0 + ml) * D_ + k0 + kq);
        AsT[kq+0][ml] = a4.x; AsT[kq+1][ml] = a4.y; AsT[kq+2][ml] = a4.z; AsT[kq+3][ml] = a4.w;
        float4 b4 = *(const float4*)(W + (size_t)(n0 + ml) * D_ + k0 + kq);
        BsT[kq+0][ml] = b4.x; BsT[kq+1][ml] = b4.y; BsT[kq+2][ml] = b4.z; BsT[kq+3][ml] = b4.w;
        __syncthreads();
        #pragma unroll
        for (int kk = 0; kk < 16; ++kk) {
            float4 av = *(const float4*)&AsT[kk][ty * 4];
            float4 bv = *(const float4*)&BsT[kk][tx * 4];
            float aa[4] = {av.x, av.y, av.z, av.w};
            float bb[4] = {bv.x, bv.y, bv.z, bv.w};
            #pragma unroll
            for (int i = 0; i < 4; ++i)
                #pragma unroll
                for (int j = 0; j < 4; ++j) acc[i][j] = fmaf(aa[i], bb[j], acc[i][j]);
        }
    }
    #pragma unroll
    for (int i = 0; i < 4; ++i) {
        float4 o4 = make_float4(acc[i][0], acc[i][1], acc[i][2], acc[i][3]);
        *(float4*)(C + (size_t)(m0 + ty * 4 + i) * D_ + n0 + tx * 4) = o4;
    }
}

// ---------------------------------------------------------------------------
// RoPE applied in-place on q and k ([B,H,S,HD] layout). token_positions == s.
// ---------------------------------------------------------------------------
__global__ __launch_bounds__(256) void rope_qk(float* __restrict__ q, float* __restrict__ k) {
    int g = blockIdx.x * 256 + threadIdx.x;
    int which = g >> 21;
    int rem   = g & ((1 << 21) - 1);
    int tt = rem & 31;
    int s  = (rem >> 5) & (S_ - 1);
    int bh = rem >> 16;
    float* buf = which ? k : q;
    size_t base = ((size_t)bh * S_ + s) * HD_ + 2 * tt;
    float x1 = buf[base], x2 = buf[base + 1];
    float inv = exp2f(-(float)tt * (13.287712379549449f / 32.0f));
    float fr  = (float)s * inv;
    float sn, cs;
    sincosf(fr, &sn, &cs);
    buf[base]     = x1 * cs - x2 * sn;
    buf[base + 1] = x1 * sn + x2 * cs;
}

// ---------------------------------------------------------------------------
// MFMA flash attention (bf16 in, fp32 acc).
// Block = 4 waves, 64 queries (wave w owns 16). K/V tiles of 64 keys in LDS.
// QK^T and PV via mfma_f32_16x16x32_bf16.
//   A-layout:  A[m = lane&15][k = (lane>>4)*8 + j]   (verified m89/m120)
//   B-layout:  B[k = (lane>>4)*8 + j][n = lane&15]
//   C-layout:  row = (lane>>4)*4 + reg, col = lane&15 (verified m89/m91)
// Kl[key][d] stride 72 (staging writes + B-frag reads bank-balanced);
// Vt[d][key] stride 72 (transposed so PV B-frags are contiguous b128);
// Pl stride 80 (quads tile banks perfectly on the A-frag round-trip).
// ---------------------------------------------------------------------------
__global__ __launch_bounds__(256) void attn_mfma(const float* __restrict__ qb,
                                                 const float* __restrict__ kb,
                                                 const float* __restrict__ vb,
                                                 float* __restrict__ att) {
    __shared__ __align__(16) short Kl[64][72];
    __shared__ __align__(16) short Vt[64][72];
    __shared__ __align__(16) short Pl[4][16][80];

    const int bx = blockIdx.x;
    const int bh = bx >> 5;            // / (S/64)
    const int qt = bx & 31;
    const int qbase = qt * 64;
    const int t  = threadIdx.x;
    const int w  = t >> 6;
    const int ln = t & 63;
    const int lane16 = ln & 15;
    const int quad   = ln >> 4;
    const int b = bh >> 4, h = bh & 15;

    const float* qg = qb + (size_t)bh * S_ * HD_;
    const float* kg = kb + (size_t)bh * S_ * HD_;
    const float* vg = vb + (size_t)bh * S_ * HD_;

    // Q fragments (A-layout), 1/sqrt(64) folded in
    bf16x8 aq[2];
    {
        const float* qrow = qg + (size_t)(qbase + w * 16 + lane16) * HD_;
        #pragma unroll
        for (int kk = 0; kk < 2; ++kk) {
            float fv[8];
            *(float4*)&fv[0] = *(const float4*)(qrow + kk * 32 + quad * 8);
            *(float4*)&fv[4] = *(const float4*)(qrow + kk * 32 + quad * 8 + 4);
            #pragma unroll
            for (int u = 0; u < 8; ++u) aq[kk][u] = f2bf(fv[u] * 0.125f);
        }
    }

    float m_[4], l_[4];
    f32x4 Of[4];
    #pragma unroll
    for (int r = 0; r < 4; ++r) { m_[r] = -1e30f; l_[r] = 0.f; }
    #pragma unroll
    for (int nt = 0; nt < 4; ++nt) Of[nt] = (f32x4){0.f, 0.f, 0.f, 0.f};

    const int ntiles = qt + 1;
    for (int jt = 0; jt < ntiles; ++jt) {
        const int j0 = jt * 64;
        __syncthreads();
        {   // stage K tile: Kl[key][d] bf16
            int r  = t >> 2;
            int c0 = (t & 3) * 16;
            const float* kr = kg + (size_t)(j0 + r) * HD_ + c0;
            float fv[16];
            *(float4*)&fv[0]  = *(const float4*)(kr);
            *(float4*)&fv[4]  = *(const float4*)(kr + 4);
            *(float4*)&fv[8]  = *(const float4*)(kr + 8);
            *(float4*)&fv[12] = *(const float4*)(kr + 12);
            bf16x8 p0, p1;
            #pragma unroll
            for (int u = 0; u < 8; ++u) { p0[u] = f2bf(fv[u]); p1[u] = f2bf(fv[u + 8]); }
            *(bf16x8*)&Kl[r][c0]     = p0;
            *(bf16x8*)&Kl[r][c0 + 8] = p1;
        }
        {   // stage V tile transposed: Vt[d][key] bf16
            int r  = t & 63;
            int c0 = (t >> 6) * 16;
            const float* vr = vg + (size_t)(j0 + r) * HD_ + c0;
            float fv[16];
            *(float4*)&fv[0]  = *(const float4*)(vr);
            *(float4*)&fv[4]  = *(const float4*)(vr + 4);
            *(float4*)&fv[8]  = *(const float4*)(vr + 8);
            *(float4*)&fv[12] = *(const float4*)(vr + 12);
            #pragma unroll
            for (int u = 0; u < 16; ++u) Vt[c0 + u][r] = f2bf(fv[u]);
        }
        __syncthreads();

        // scores: S[16 q][64 keys] per wave, 8 MFMAs
        f32x4 Sf[4];
        #pragma unroll
        for (int nt = 0; nt < 4; ++nt) {
            bf16x8 bk0 = *(const bf16x8*)&Kl[nt * 16 + lane16][quad * 8];
            bf16x8 bk1 = *(const bf16x8*)&Kl[nt * 16 + lane16][32 + quad * 8];
            f32x4 z = (f32x4){0.f, 0.f, 0.f, 0.f};
            z = __builtin_amdgcn_mfma_f32_16x16x32_bf16(aq[0], bk0, z, 0, 0, 0);
            z = __builtin_amdgcn_mfma_f32_16x16x32_bf16(aq[1], bk1, z, 0, 0, 0);
            Sf[nt] = z;
        }

        if (jt == qt) {   // diagonal tile: causal mask
            #pragma unroll
            for (int nt = 0; nt < 4; ++nt)
                #pragma unroll
                for (int r = 0; r < 4; ++r) {
                    int key = j0 + nt * 16 + lane16;
                    int qq  = qbase + w * 16 + quad * 4 + r;
                    if (key > qq) Sf[nt][r] = -1e30f;
                }
        }

        // online softmax per query row (row spread over 16 lanes of same quad)
        float alpha[4];
        #pragma unroll
        for (int r = 0; r < 4; ++r) {
            float mx = fmaxf(fmaxf(Sf[0][r], Sf[1][r]), fmaxf(Sf[2][r], Sf[3][r]));
            #pragma unroll
            for (int off = 1; off < 16; off <<= 1) mx = fmaxf(mx, __shfl_xor(mx, off, 64));
            float mn = fmaxf(m_[r], mx);
            float p0 = __expf(Sf[0][r] - mn);
            float p1 = __expf(Sf[1][r] - mn);
            float p2 = __expf(Sf[2][r] - mn);
            float p3 = __expf(Sf[3][r] - mn);
            float ts = (p0 + p1) + (p2 + p3);
            #pragma unroll
            for (int off = 1; off < 16; off <<= 1) ts += __shfl_xor(ts, off, 64);
            alpha[r] = __expf(m_[r] - mn);    // first tile: exp(-1e30-mn) -> 0
            l_[r] = l_[r] * alpha[r] + ts;
            m_[r] = mn;
            int row = quad * 4 + r;
            Pl[w][row][lane16]      = f2bf(p0);
            Pl[w][row][16 + lane16] = f2bf(p1);
            Pl[w][row][32 + lane16] = f2bf(p2);
            Pl[w][row][48 + lane16] = f2bf(p3);
        }

        // rescale O, then PV (wave-private Pl: no barrier needed)
        #pragma unroll
        for (int nt = 0; nt < 4; ++nt)
            #pragma unroll
            for (int r = 0; r < 4; ++r) Of[nt][r] *= alpha[r];

        #pragma unroll
        for (int kk = 0; kk < 2; ++kk) {
            bf16x8 ap = *(const bf16x8*)&Pl[w][lane16][kk * 32 + quad * 8];
            #pragma unroll
            for (int nt = 0; nt < 4; ++nt) {
                bf16x8 bv = *(const bf16x8*)&Vt[nt * 16 + lane16][kk * 32 + quad * 8];
                Of[nt] = __builtin_amdgcn_mfma_f32_16x16x32_bf16(ap, bv, Of[nt], 0, 0, 0);
            }
        }
    }

    // epilogue: att in [B,S,H*HD]
    #pragma unroll
    for (int r = 0; r < 4; ++r) {
        int s = qbase + w * 16 + quad * 4 + r;
        float inv_l = 1.0f / l_[r];
        float* dst = att + ((size_t)(b * S_ + s)) * D_ + h * HD_;
        #pragma unroll
        for (int nt = 0; nt < 4; ++nt) dst[nt * 16 + lane16] = Of[nt][r] * inv_l;
    }
}

// ---------------------------------------------------------------------------
extern "C" void kernel_launch(void* const* d_in, const int* in_sizes, int n_in,
                              void* d_out, int out_size, void* d_ws, size_t ws_size,
                              hipStream_t stream) {
    const float* X    = (const float*)d_in[0];   // [B,S,D] fp32
    const float* Wqkv = (const float*)d_in[2];   // [3D,D] fp32
    const float* Wo   = (const float*)d_in[3];   // [D,D] fp32
    float* out = (float*)d_out;

    float* ws = (float*)d_ws;
    const size_t QS = (size_t)B_ * H_ * S_ * HD_;   // 4,194,304 floats
    float* q   = ws;
    float* k   = ws + QS;
    float* v   = ws + 2 * QS;
    float* att = ws + 3 * QS;

    dim3 blk(16, 16);
    gemm_qkv<<<dim3(NE_ / 64, M_ / 64), blk, 0, stream>>>(X, Wqkv, q, k, v);
    rope_qk<<<(unsigned)(QS / 256), 256, 0, stream>>>(q, k);
    attn_mfma<<<B_ * H_ * (S_ / 64), 256, 0, stream>>>(q, k, v, att);
    gemm_out<<<dim3(D_ / 64, M_ / 64), blk, 0, stream>>>(att, Wo, out);
}

// Round 4
// 525.597 us; speedup vs baseline: 2.8147x; 1.2965x over previous
//
#include <hip/hip_runtime.h>
#include <hip/hip_bf16.h>
#include <math.h>

// Problem constants (fixed by setup_inputs)
#define B_  2
#define S_  2048
#define D_  1024
#define H_  16
#define HD_ 64
#define NE_ 3072   // 3*D
#define M_  4096   // B*S

typedef unsigned short ushort_t;
typedef __attribute__((ext_vector_type(8))) short bf16x8;
typedef __attribute__((ext_vector_type(4))) float f32x4;

__device__ __forceinline__ short f2bf(float f) {
    union { float f; unsigned u; } v; v.f = f;
    unsigned u = v.u;
    u += 0x7fffu + ((u >> 16) & 1u);   // round-to-nearest-even
    return (short)(u >> 16);
}
__device__ __forceinline__ float bf2f(short h) {
    union { unsigned u; float f; } v;
    v.u = ((unsigned)(unsigned short)h) << 16;
    return v.f;
}

// async global->LDS, 16B per lane; LDS dest = wave-uniform base + lane*16
__device__ __forceinline__ void async16(const ushort_t* g, ushort_t* l) {
    __builtin_amdgcn_global_load_lds(
        (const __attribute__((address_space(1))) void*)g,
        (__attribute__((address_space(3))) void*)l,
        16, 0, 0);
}

// ---------------------------------------------------------------------------
// fp32 -> bf16 conversion (8 elems/thread) — used for Wo only
// ---------------------------------------------------------------------------
__global__ __launch_bounds__(256) void cvt_bf16(const float* __restrict__ s,
                                                ushort_t* __restrict__ d, int n8) {
    int i = blockIdx.x * 256 + threadIdx.x;
    if (i >= n8) return;
    const float4* sp = (const float4*)s;
    float4 a = sp[2 * (size_t)i], b = sp[2 * (size_t)i + 1];
    bf16x8 o;
    o[0] = f2bf(a.x); o[1] = f2bf(a.y); o[2] = f2bf(a.z); o[3] = f2bf(a.w);
    o[4] = f2bf(b.x); o[5] = f2bf(b.y); o[6] = f2bf(b.z); o[7] = f2bf(b.w);
    *(bf16x8*)(d + 8 * (size_t)i) = o;
}

// ---------------------------------------------------------------------------
// Split-precision QKV GEMM with fused RoPE epilogue.
// C[m][n] = sum_k X[m][k]*W[n][k], computed as 3-pass bf16 MFMA:
//   x = xh + xl (bf16 split), w = wh + wl;  acc += xh*wh + xh*wl + xl*wh
// -> ~2^-17 relative input error (fp32-grade). fp32 inputs are split during
// LDS staging (VGPR path). 128x128 tile, BK=64, XOR-swizzled LDS
// (phys chunk = logical ^ (row&7)) for conflict-free b128 frag reads.
// Epilogue: RoPE via __shfl_xor pair exchange; q scaled 0.125, stored as
// bf16 hi+lo pair; k,v single bf16. Layout [B,H,S,HD].
// ---------------------------------------------------------------------------
__global__ __launch_bounds__(256) void gemm_qkv_split(const float* __restrict__ X,
                                                      const float* __restrict__ W,
                                                      ushort_t* __restrict__ qhi,
                                                      ushort_t* __restrict__ qlo,
                                                      ushort_t* __restrict__ kb,
                                                      ushort_t* __restrict__ vb) {
    __shared__ __align__(16) ushort_t Ah[128 * 64];
    __shared__ __align__(16) ushort_t Al[128 * 64];
    __shared__ __align__(16) ushort_t Bh[128 * 64];
    __shared__ __align__(16) ushort_t Bl[128 * 64];
    const int t = threadIdx.x;
    const int w = t >> 6, ln = t & 63;
    const int lane16 = ln & 15, quad = ln >> 4;
    const int wm = w >> 1, wn = w & 1;
    const int m0 = blockIdx.y * 128, n0 = blockIdx.x * 128;
    const int srow = t >> 1;         // staging row 0..127
    const int shalf = t & 1;         // staging col-half (32 floats each)

    f32x4 acc[4][4];
    #pragma unroll
    for (int i = 0; i < 4; ++i)
        #pragma unroll
        for (int j = 0; j < 4; ++j) acc[i][j] = (f32x4){0.f, 0.f, 0.f, 0.f};

    for (int k0 = 0; k0 < D_; k0 += 64) {
        __syncthreads();
        {   // stage A (X) split
            const float* src = X + (size_t)(m0 + srow) * D_ + k0 + shalf * 32;
            float f[32];
            #pragma unroll
            for (int u = 0; u < 8; ++u) *(float4*)&f[u * 4] = *(const float4*)(src + u * 4);
            #pragma unroll
            for (int c = 0; c < 4; ++c) {
                bf16x8 hi, lo;
                #pragma unroll
                for (int e = 0; e < 8; ++e) {
                    float vv = f[c * 8 + e];
                    short hh = f2bf(vv);
                    hi[e] = hh; lo[e] = f2bf(vv - bf2f(hh));
                }
                int phys = (shalf * 4 + c) ^ (srow & 7);
                *(bf16x8*)&Ah[srow * 64 + phys * 8] = hi;
                *(bf16x8*)&Al[srow * 64 + phys * 8] = lo;
            }
        }
        {   // stage B (W) split
            const float* src = W + (size_t)(n0 + srow) * D_ + k0 + shalf * 32;
            float f[32];
            #pragma unroll
            for (int u = 0; u < 8; ++u) *(float4*)&f[u * 4] = *(const float4*)(src + u * 4);
            #pragma unroll
            for (int c = 0; c < 4; ++c) {
                bf16x8 hi, lo;
                #pragma unroll
                for (int e = 0; e < 8; ++e) {
                    float vv = f[c * 8 + e];
                    short hh = f2bf(vv);
                    hi[e] = hh; lo[e] = f2bf(vv - bf2f(hh));
                }
                int phys = (shalf * 4 + c) ^ (srow & 7);
                *(bf16x8*)&Bh[srow * 64 + phys * 8] = hi;
                *(bf16x8*)&Bl[srow * 64 + phys * 8] = lo;
            }
        }
        __syncthreads();
        #pragma unroll
        for (int kc = 0; kc < 2; ++kc) {
            bf16x8 ah[4], al[4], bh[4], bl[4];
            #pragma unroll
            for (int i = 0; i < 4; ++i) {
                int ra = wm * 64 + i * 16 + lane16;
                int ca = (kc * 4 + quad) ^ (ra & 7);
                ah[i] = *(const bf16x8*)&Ah[ra * 64 + ca * 8];
                al[i] = *(const bf16x8*)&Al[ra * 64 + ca * 8];
                int rb = wn * 64 + i * 16 + lane16;
                int cb = (kc * 4 + quad) ^ (rb & 7);
                bh[i] = *(const bf16x8*)&Bh[rb * 64 + cb * 8];
                bl[i] = *(const bf16x8*)&Bl[rb * 64 + cb * 8];
            }
            #pragma unroll
            for (int i = 0; i < 4; ++i)
                #pragma unroll
                for (int j = 0; j < 4; ++j) {
                    acc[i][j] = __builtin_amdgcn_mfma_f32_16x16x32_bf16(ah[i], bh[j], acc[i][j], 0, 0, 0);
                    acc[i][j] = __builtin_amdgcn_mfma_f32_16x16x32_bf16(ah[i], bl[j], acc[i][j], 0, 0, 0);
                    acc[i][j] = __builtin_amdgcn_mfma_f32_16x16x32_bf16(al[i], bh[j], acc[i][j], 0, 0, 0);
                }
        }
    }

    // epilogue: fused RoPE (pair partner is adjacent lane), scatter to q/k/v
    const bool odd = (lane16 & 1) != 0;
    #pragma unroll
    for (int j = 0; j < 4; ++j) {
        int nb = n0 + wn * 64 + j * 16;
        int c  = nb >> 10;               // 0=q 1=k 2=v (uniform per block)
        int h  = (nb >> 6) & 15;
        int dcol = (nb & 63) + lane16;   // 0..63
        int tt = dcol >> 1;
        float inv = exp2f(-(float)tt * (13.287712379549449f / 32.0f));
        #pragma unroll
        for (int i = 0; i < 4; ++i)
            #pragma unroll
            for (int r = 0; r < 4; ++r) {
                int m = m0 + wm * 64 + i * 16 + quad * 4 + r;
                int b = m >> 11, s = m & (S_ - 1);
                size_t idx = ((size_t)((b * H_ + h) * S_ + s)) * HD_ + dcol;
                float val = acc[i][j][r];
                if (c < 2) {
                    float part = __shfl_xor(val, 1, 64);
                    float ang = (float)s * inv;
                    float sn, cs;
                    sincosf(ang, &sn, &cs);
                    float x1 = odd ? part : val;
                    float x2 = odd ? val : part;
                    float res = odd ? fmaf(x1, sn, x2 * cs) : fmaf(x1, cs, -x2 * sn);
                    if (c == 0) {
                        float vs = res * 0.125f;         // fold 1/sqrt(hd)
                        short hh = f2bf(vs);
                        qhi[idx] = (ushort_t)hh;
                        qlo[idx] = (ushort_t)f2bf(vs - bf2f(hh));
                    } else {
                        kb[idx] = (ushort_t)f2bf(res);
                    }
                } else {
                    vb[idx] = (ushort_t)f2bf(val);
                }
            }
    }
}

// ---------------------------------------------------------------------------
// O-projection (single-pass bf16 MFMA, m97 structure): A=attb, W=Wob, C=out fp32
// ---------------------------------------------------------------------------
__global__ __launch_bounds__(256) void gemm_out_bf16(const ushort_t* __restrict__ Ag,
                                                     const ushort_t* __restrict__ Wg,
                                                     float* __restrict__ C) {
    __shared__ ushort_t As[128 * 64];
    __shared__ ushort_t Bs[128 * 64];
    const int t = threadIdx.x;
    const int w = t >> 6, ln = t & 63;
    const int lane16 = ln & 15, quad = ln >> 4;
    const int wm = w >> 1, wn = w & 1;
    const int m0 = blockIdx.y * 128, n0 = blockIdx.x * 128;
    const int srow8 = ln >> 3;
    const int schunk = (ln & 7) ^ srow8;
    f32x4 acc[4][4];
    #pragma unroll
    for (int i = 0; i < 4; ++i)
        #pragma unroll
        for (int j = 0; j < 4; ++j) acc[i][j] = (f32x4){0.f, 0.f, 0.f, 0.f};
    for (int k0 = 0; k0 < D_; k0 += 64) {
        __syncthreads();
        #pragma unroll
        for (int i = 0; i < 4; ++i) {
            int rr = (i * 4 + w) * 8 + srow8;
            async16(Ag + (size_t)(m0 + rr) * D_ + k0 + schunk * 8, As + (i * 4 + w) * 512);
            async16(Wg + (size_t)(n0 + rr) * D_ + k0 + schunk * 8, Bs + (i * 4 + w) * 512);
        }
        __syncthreads();
        #pragma unroll
        for (int kc = 0; kc < 2; ++kc) {
            bf16x8 af[4], bfr[4];
            #pragma unroll
            for (int i = 0; i < 4; ++i) {
                int ra = wm * 64 + i * 16 + lane16;
                int ca = (kc * 4 + quad) ^ (ra & 7);
                af[i] = *(const bf16x8*)&As[ra * 64 + ca * 8];
                int rb = wn * 64 + i * 16 + lane16;
                int cb = (kc * 4 + quad) ^ (rb & 7);
                bfr[i] = *(const bf16x8*)&Bs[rb * 64 + cb * 8];
            }
            #pragma unroll
            for (int i = 0; i < 4; ++i)
                #pragma unroll
                for (int j = 0; j < 4; ++j)
                    acc[i][j] = __builtin_amdgcn_mfma_f32_16x16x32_bf16(af[i], bfr[j], acc[i][j], 0, 0, 0);
        }
    }
    #pragma unroll
    for (int i = 0; i < 4; ++i)
        #pragma unroll
        for (int j = 0; j < 4; ++j)
            #pragma unroll
            for (int r = 0; r < 4; ++r) {
                int m = m0 + wm * 64 + i * 16 + quad * 4 + r;
                int n = n0 + wn * 64 + j * 16 + lane16;
                C[(size_t)m * D_ + n] = acc[i][j][r];
            }
}

// ---------------------------------------------------------------------------
// MFMA flash attention, bf16 in/out. q supplied as hi+lo bf16 pair
// (pre-scaled by 0.125), scores use 2-term q for fp32-grade q precision.
// Block = 4 waves, 64 queries. Layouts verified in R2.
// ---------------------------------------------------------------------------
__global__ __launch_bounds__(256) void attn_mfma(const ushort_t* __restrict__ qhib,
                                                 const ushort_t* __restrict__ qlob,
                                                 const ushort_t* __restrict__ kb,
                                                 const ushort_t* __restrict__ vb,
                                                 ushort_t* __restrict__ att) {
    __shared__ __align__(16) short Kl[64][72];
    __shared__ __align__(16) short Vt[64][72];
    __shared__ __align__(16) short Pl[4][16][80];

    const int bx = blockIdx.x;
    const int bh = bx >> 5;            // / (S/64)
    const int qt = bx & 31;
    const int qbase = qt * 64;
    const int t  = threadIdx.x;
    const int w  = t >> 6;
    const int ln = t & 63;
    const int lane16 = ln & 15;
    const int quad   = ln >> 4;
    const int b = bh >> 4, h = bh & 15;

    const ushort_t* qhg = qhib + (size_t)bh * S_ * HD_;
    const ushort_t* qlg = qlob + (size_t)bh * S_ * HD_;
    const ushort_t* kg  = kb   + (size_t)bh * S_ * HD_;
    const ushort_t* vg  = vb   + (size_t)bh * S_ * HD_;

    // Q fragments (A-layout), hi+lo
    bf16x8 aqh[2], aql[2];
    {
        size_t ro = (size_t)(qbase + w * 16 + lane16) * HD_;
        aqh[0] = *(const bf16x8*)(qhg + ro + quad * 8);
        aqh[1] = *(const bf16x8*)(qhg + ro + 32 + quad * 8);
        aql[0] = *(const bf16x8*)(qlg + ro + quad * 8);
        aql[1] = *(const bf16x8*)(qlg + ro + 32 + quad * 8);
    }

    float m_[4], l_[4];
    f32x4 Of[4];
    #pragma unroll
    for (int r = 0; r < 4; ++r) { m_[r] = -1e30f; l_[r] = 0.f; }
    #pragma unroll
    for (int nt = 0; nt < 4; ++nt) Of[nt] = (f32x4){0.f, 0.f, 0.f, 0.f};

    const int ntiles = qt + 1;
    for (int jt = 0; jt < ntiles; ++jt) {
        const int j0 = jt * 64;
        __syncthreads();
        {   // stage K tile: Kl[key][d]
            int r  = t >> 2;
            int c0 = (t & 3) * 16;
            const ushort_t* kr = kg + (size_t)(j0 + r) * HD_ + c0;
            bf16x8 p0 = *(const bf16x8*)(kr);
            bf16x8 p1 = *(const bf16x8*)(kr + 8);
            *(bf16x8*)&Kl[r][c0]     = p0;
            *(bf16x8*)&Kl[r][c0 + 8] = p1;
        }
        {   // stage V tile transposed: Vt[d][key]
            int r  = t & 63;
            int c0 = (t >> 6) * 16;
            const ushort_t* vr = vg + (size_t)(j0 + r) * HD_ + c0;
            bf16x8 v0 = *(const bf16x8*)(vr);
            bf16x8 v1 = *(const bf16x8*)(vr + 8);
            #pragma unroll
            for (int u = 0; u < 8; ++u) Vt[c0 + u][r] = v0[u];
            #pragma unroll
            for (int u = 0; u < 8; ++u) Vt[c0 + 8 + u][r] = v1[u];
        }
        __syncthreads();

        // scores: S[16 q][64 keys] per wave, 2-term q
        f32x4 Sf[4];
        #pragma unroll
        for (int nt = 0; nt < 4; ++nt) {
            bf16x8 bk0 = *(const bf16x8*)&Kl[nt * 16 + lane16][quad * 8];
            bf16x8 bk1 = *(const bf16x8*)&Kl[nt * 16 + lane16][32 + quad * 8];
            f32x4 z = (f32x4){0.f, 0.f, 0.f, 0.f};
            z = __builtin_amdgcn_mfma_f32_16x16x32_bf16(aqh[0], bk0, z, 0, 0, 0);
            z = __builtin_amdgcn_mfma_f32_16x16x32_bf16(aql[0], bk0, z, 0, 0, 0);
            z = __builtin_amdgcn_mfma_f32_16x16x32_bf16(aqh[1], bk1, z, 0, 0, 0);
            z = __builtin_amdgcn_mfma_f32_16x16x32_bf16(aql[1], bk1, z, 0, 0, 0);
            Sf[nt] = z;
        }

        if (jt == qt) {   // diagonal tile: causal mask
            #pragma unroll
            for (int nt = 0; nt < 4; ++nt)
                #pragma unroll
                for (int r = 0; r < 4; ++r) {
                    int key = j0 + nt * 16 + lane16;
                    int qq  = qbase + w * 16 + quad * 4 + r;
                    if (key > qq) Sf[nt][r] = -1e30f;
                }
        }

        // online softmax per query row
        float alpha[4];
        #pragma unroll
        for (int r = 0; r < 4; ++r) {
            float mx = fmaxf(fmaxf(Sf[0][r], Sf[1][r]), fmaxf(Sf[2][r], Sf[3][r]));
            #pragma unroll
            for (int off = 1; off < 16; off <<= 1) mx = fmaxf(mx, __shfl_xor(mx, off, 64));
            float mn = fmaxf(m_[r], mx);
            float p0 = __expf(Sf[0][r] - mn);
            float p1 = __expf(Sf[1][r] - mn);
            float p2 = __expf(Sf[2][r] - mn);
            float p3 = __expf(Sf[3][r] - mn);
            float ts = (p0 + p1) + (p2 + p3);
            #pragma unroll
            for (int off = 1; off < 16; off <<= 1) ts += __shfl_xor(ts, off, 64);
            alpha[r] = __expf(m_[r] - mn);
            l_[r] = l_[r] * alpha[r] + ts;
            m_[r] = mn;
            int row = quad * 4 + r;
            Pl[w][row][lane16]      = f2bf(p0);
            Pl[w][row][16 + lane16] = f2bf(p1);
            Pl[w][row][32 + lane16] = f2bf(p2);
            Pl[w][row][48 + lane16] = f2bf(p3);
        }

        // rescale O, then PV (wave-private Pl: no barrier needed)
        #pragma unroll
        for (int nt = 0; nt < 4; ++nt)
            #pragma unroll
            for (int r = 0; r < 4; ++r) Of[nt][r] *= alpha[r];

        #pragma unroll
        for (int kk = 0; kk < 2; ++kk) {
            bf16x8 ap = *(const bf16x8*)&Pl[w][lane16][kk * 32 + quad * 8];
            #pragma unroll
            for (int nt = 0; nt < 4; ++nt) {
                bf16x8 bv = *(const bf16x8*)&Vt[nt * 16 + lane16][kk * 32 + quad * 8];
                Of[nt] = __builtin_amdgcn_mfma_f32_16x16x32_bf16(ap, bv, Of[nt], 0, 0, 0);
            }
        }
    }

    // epilogue: att bf16 in [B,S,H*HD]
    #pragma unroll
    for (int r = 0; r < 4; ++r) {
        int s = qbase + w * 16 + quad * 4 + r;
        float inv_l = 1.0f / l_[r];
        ushort_t* dst = att + ((size_t)(b * S_ + s)) * D_ + h * HD_;
        #pragma unroll
        for (int nt = 0; nt < 4; ++nt)
            dst[nt * 16 + lane16] = (ushort_t)f2bf(Of[nt][r] * inv_l);
    }
}

// ---------------------------------------------------------------------------
extern "C" void kernel_launch(void* const* d_in, const int* in_sizes, int n_in,
                              void* d_out, int out_size, void* d_ws, size_t ws_size,
                              hipStream_t stream) {
    const float* X    = (const float*)d_in[0];   // [B,S,D] fp32
    const float* Wqkv = (const float*)d_in[2];   // [3D,D] fp32
    const float* Wo   = (const float*)d_in[3];   // [D,D] fp32
    float* out = (float*)d_out;

    ushort_t* ws = (ushort_t*)d_ws;
    const size_t QS = (size_t)B_ * H_ * S_ * HD_;   // 4,194,304 elems
    ushort_t* qhi  = ws;
    ushort_t* qlo  = ws + QS;
    ushort_t* kbuf = ws + 2 * QS;
    ushort_t* vbuf = ws + 3 * QS;
    ushort_t* attb = ws + 4 * QS;                   // [4096][1024]
    ushort_t* Wob  = ws + 5 * QS;                   // [1024][1024]
    // total 5*QS + 1M = 21M elems = 42 MB

    cvt_bf16<<<512, 256, 0, stream>>>(Wo, Wob, (D_ * D_) / 8);
    gemm_qkv_split<<<dim3(NE_ / 128, M_ / 128), 256, 0, stream>>>(X, Wqkv, qhi, qlo, kbuf, vbuf);
    attn_mfma<<<B_ * H_ * (S_ / 64), 256, 0, stream>>>(qhi, qlo, kbuf, vbuf, attb);
    gemm_out_bf16<<<dim3(D_ / 128, M_ / 128), 256, 0, stream>>>(attb, Wob, out);
}

// Round 5
// 435.880 us; speedup vs baseline: 3.3940x; 1.2058x over previous
//
#include <hip/hip_runtime.h>
#include <hip/hip_bf16.h>
#include <math.h>

// Problem constants (fixed by setup_inputs)
#define B_  2
#define S_  2048
#define D_  1024
#define H_  16
#define HD_ 64
#define NE_ 3072   // 3*D
#define M_  4096   // B*S

typedef unsigned short ushort_t;
typedef __attribute__((ext_vector_type(8))) short bf16x8;
typedef __attribute__((ext_vector_type(4))) float f32x4;

__device__ __forceinline__ short f2bf(float f) {
    union { float f; unsigned u; } v; v.f = f;
    unsigned u = v.u;
    u += 0x7fffu + ((u >> 16) & 1u);   // round-to-nearest-even
    return (short)(u >> 16);
}
__device__ __forceinline__ float bf2f(short h) {
    union { unsigned u; float f; } v;
    v.u = ((unsigned)(unsigned short)h) << 16;
    return v.f;
}

// register-resident hi/lo bf16 split of 8 floats (NO local arrays -> no scratch)
__device__ __forceinline__ void split_f4(float4 a, float4 b, bf16x8* hi, bf16x8* lo) {
    short h;
    h = f2bf(a.x); (*hi)[0] = h; (*lo)[0] = f2bf(a.x - bf2f(h));
    h = f2bf(a.y); (*hi)[1] = h; (*lo)[1] = f2bf(a.y - bf2f(h));
    h = f2bf(a.z); (*hi)[2] = h; (*lo)[2] = f2bf(a.z - bf2f(h));
    h = f2bf(a.w); (*hi)[3] = h; (*lo)[3] = f2bf(a.w - bf2f(h));
    h = f2bf(b.x); (*hi)[4] = h; (*lo)[4] = f2bf(b.x - bf2f(h));
    h = f2bf(b.y); (*hi)[5] = h; (*lo)[5] = f2bf(b.y - bf2f(h));
    h = f2bf(b.z); (*hi)[6] = h; (*lo)[6] = f2bf(b.z - bf2f(h));
    h = f2bf(b.w); (*hi)[7] = h; (*lo)[7] = f2bf(b.w - bf2f(h));
}

// async global->LDS, 16B per lane; LDS dest = wave-uniform base + lane*16
__device__ __forceinline__ void async16(const ushort_t* g, ushort_t* l) {
    __builtin_amdgcn_global_load_lds(
        (const __attribute__((address_space(1))) void*)g,
        (__attribute__((address_space(3))) void*)l,
        16, 0, 0);
}

// ---------------------------------------------------------------------------
// fp32 -> bf16 conversion (8 elems/thread) — used for Wo only
// ---------------------------------------------------------------------------
__global__ __launch_bounds__(256) void cvt_bf16(const float* __restrict__ s,
                                                ushort_t* __restrict__ d, int n8) {
    int i = blockIdx.x * 256 + threadIdx.x;
    if (i >= n8) return;
    const float4* sp = (const float4*)s;
    float4 a = sp[2 * (size_t)i], b = sp[2 * (size_t)i + 1];
    bf16x8 o;
    o[0] = f2bf(a.x); o[1] = f2bf(a.y); o[2] = f2bf(a.z); o[3] = f2bf(a.w);
    o[4] = f2bf(b.x); o[5] = f2bf(b.y); o[6] = f2bf(b.z); o[7] = f2bf(b.w);
    *(bf16x8*)(d + 8 * (size_t)i) = o;
}

// ---------------------------------------------------------------------------
// Split-precision QKV GEMM with fused RoPE epilogue.
// C[m][n] = sum_k X[m][k]*W[n][k], 3-pass bf16 MFMA (xh*wh + xh*wl + xl*wh)
// -> fp32-grade input precision. Inputs split during LDS staging, all in
// registers. 128x128 tile, BK=64, XOR-swizzled LDS (phys chunk = c^(row&7)).
// Epilogue: fused RoPE via __shfl_xor; q scaled 0.125, stored bf16 hi+lo;
// k,v single bf16. Layout [B,H,S,HD].
// ---------------------------------------------------------------------------
__global__ __launch_bounds__(256) void gemm_qkv_split(const float* __restrict__ X,
                                                      const float* __restrict__ W,
                                                      ushort_t* __restrict__ qhi,
                                                      ushort_t* __restrict__ qlo,
                                                      ushort_t* __restrict__ kb,
                                                      ushort_t* __restrict__ vb) {
    __shared__ __align__(16) ushort_t Ah[128 * 64];
    __shared__ __align__(16) ushort_t Al[128 * 64];
    __shared__ __align__(16) ushort_t Bh[128 * 64];
    __shared__ __align__(16) ushort_t Bl[128 * 64];
    const int t = threadIdx.x;
    const int w = t >> 6, ln = t & 63;
    const int lane16 = ln & 15, quad = ln >> 4;
    const int wm = w >> 1, wn = w & 1;
    const int m0 = blockIdx.y * 128, n0 = blockIdx.x * 128;
    const int srow = t >> 1;         // staging row 0..127
    const int shalf = t & 1;         // staging col-half (32 floats each)

    f32x4 acc[4][4];
    #pragma unroll
    for (int i = 0; i < 4; ++i)
        #pragma unroll
        for (int j = 0; j < 4; ++j) acc[i][j] = (f32x4){0.f, 0.f, 0.f, 0.f};

    for (int k0 = 0; k0 < D_; k0 += 64) {
        __syncthreads();
        {   // stage A (X) split — register-resident
            const float* src = X + (size_t)(m0 + srow) * D_ + k0 + shalf * 32;
            #pragma unroll
            for (int c = 0; c < 4; ++c) {
                float4 fa = *(const float4*)(src + c * 8);
                float4 fb = *(const float4*)(src + c * 8 + 4);
                bf16x8 hi, lo;
                split_f4(fa, fb, &hi, &lo);
                int phys = (shalf * 4 + c) ^ (srow & 7);
                *(bf16x8*)&Ah[srow * 64 + phys * 8] = hi;
                *(bf16x8*)&Al[srow * 64 + phys * 8] = lo;
            }
        }
        {   // stage B (W) split — register-resident
            const float* src = W + (size_t)(n0 + srow) * D_ + k0 + shalf * 32;
            #pragma unroll
            for (int c = 0; c < 4; ++c) {
                float4 fa = *(const float4*)(src + c * 8);
                float4 fb = *(const float4*)(src + c * 8 + 4);
                bf16x8 hi, lo;
                split_f4(fa, fb, &hi, &lo);
                int phys = (shalf * 4 + c) ^ (srow & 7);
                *(bf16x8*)&Bh[srow * 64 + phys * 8] = hi;
                *(bf16x8*)&Bl[srow * 64 + phys * 8] = lo;
            }
        }
        __syncthreads();
        #pragma unroll
        for (int kc = 0; kc < 2; ++kc) {
            bf16x8 ah[4], al[4], bh[4], bl[4];
            #pragma unroll
            for (int i = 0; i < 4; ++i) {
                int ra = wm * 64 + i * 16 + lane16;
                int ca = (kc * 4 + quad) ^ (ra & 7);
                ah[i] = *(const bf16x8*)&Ah[ra * 64 + ca * 8];
                al[i] = *(const bf16x8*)&Al[ra * 64 + ca * 8];
                int rb = wn * 64 + i * 16 + lane16;
                int cb = (kc * 4 + quad) ^ (rb & 7);
                bh[i] = *(const bf16x8*)&Bh[rb * 64 + cb * 8];
                bl[i] = *(const bf16x8*)&Bl[rb * 64 + cb * 8];
            }
            #pragma unroll
            for (int i = 0; i < 4; ++i)
                #pragma unroll
                for (int j = 0; j < 4; ++j) {
                    acc[i][j] = __builtin_amdgcn_mfma_f32_16x16x32_bf16(ah[i], bh[j], acc[i][j], 0, 0, 0);
                    acc[i][j] = __builtin_amdgcn_mfma_f32_16x16x32_bf16(ah[i], bl[j], acc[i][j], 0, 0, 0);
                    acc[i][j] = __builtin_amdgcn_mfma_f32_16x16x32_bf16(al[i], bh[j], acc[i][j], 0, 0, 0);
                }
        }
    }

    // epilogue: fused RoPE (pair partner is adjacent lane), scatter to q/k/v
    const bool odd = (lane16 & 1) != 0;
    #pragma unroll
    for (int j = 0; j < 4; ++j) {
        int nb = n0 + wn * 64 + j * 16;
        int c  = nb >> 10;               // 0=q 1=k 2=v (uniform per block)
        int h  = (nb >> 6) & 15;
        int dcol = (nb & 63) + lane16;   // 0..63
        int tt = dcol >> 1;
        float inv = exp2f(-(float)tt * (13.287712379549449f / 32.0f));
        #pragma unroll
        for (int i = 0; i < 4; ++i)
            #pragma unroll
            for (int r = 0; r < 4; ++r) {
                int m = m0 + wm * 64 + i * 16 + quad * 4 + r;
                int b = m >> 11, s = m & (S_ - 1);
                size_t idx = ((size_t)((b * H_ + h) * S_ + s)) * HD_ + dcol;
                float val = acc[i][j][r];
                if (c < 2) {
                    float part = __shfl_xor(val, 1, 64);
                    float ang = (float)s * inv;
                    float sn = __sinf(ang);        // pure-expression intrinsics:
                    float cs = __cosf(ang);        // no pointer outs, no scratch
                    float x1 = odd ? part : val;
                    float x2 = odd ? val : part;
                    float res = odd ? fmaf(x1, sn, x2 * cs) : fmaf(x1, cs, -x2 * sn);
                    if (c == 0) {
                        float vs = res * 0.125f;         // fold 1/sqrt(hd)
                        short hh = f2bf(vs);
                        qhi[idx] = (ushort_t)hh;
                        qlo[idx] = (ushort_t)f2bf(vs - bf2f(hh));
                    } else {
                        kb[idx] = (ushort_t)f2bf(res);
                    }
                } else {
                    vb[idx] = (ushort_t)f2bf(val);
                }
            }
    }
}

// ---------------------------------------------------------------------------
// O-projection (single-pass bf16 MFMA, m97 structure): A=attb, W=Wob, C=out fp32
// ---------------------------------------------------------------------------
__global__ __launch_bounds__(256) void gemm_out_bf16(const ushort_t* __restrict__ Ag,
                                                     const ushort_t* __restrict__ Wg,
                                                     float* __restrict__ C) {
    __shared__ ushort_t As[128 * 64];
    __shared__ ushort_t Bs[128 * 64];
    const int t = threadIdx.x;
    const int w = t >> 6, ln = t & 63;
    const int lane16 = ln & 15, quad = ln >> 4;
    const int wm = w >> 1, wn = w & 1;
    const int m0 = blockIdx.y * 128, n0 = blockIdx.x * 128;
    const int srow8 = ln >> 3;
    const int schunk = (ln & 7) ^ srow8;
    f32x4 acc[4][4];
    #pragma unroll
    for (int i = 0; i < 4; ++i)
        #pragma unroll
        for (int j = 0; j < 4; ++j) acc[i][j] = (f32x4){0.f, 0.f, 0.f, 0.f};
    for (int k0 = 0; k0 < D_; k0 += 64) {
        __syncthreads();
        #pragma unroll
        for (int i = 0; i < 4; ++i) {
            int rr = (i * 4 + w) * 8 + srow8;
            async16(Ag + (size_t)(m0 + rr) * D_ + k0 + schunk * 8, As + (i * 4 + w) * 512);
            async16(Wg + (size_t)(n0 + rr) * D_ + k0 + schunk * 8, Bs + (i * 4 + w) * 512);
        }
        __syncthreads();
        #pragma unroll
        for (int kc = 0; kc < 2; ++kc) {
            bf16x8 af[4], bfr[4];
            #pragma unroll
            for (int i = 0; i < 4; ++i) {
                int ra = wm * 64 + i * 16 + lane16;
                int ca = (kc * 4 + quad) ^ (ra & 7);
                af[i] = *(const bf16x8*)&As[ra * 64 + ca * 8];
                int rb = wn * 64 + i * 16 + lane16;
                int cb = (kc * 4 + quad) ^ (rb & 7);
                bfr[i] = *(const bf16x8*)&Bs[rb * 64 + cb * 8];
            }
            #pragma unroll
            for (int i = 0; i < 4; ++i)
                #pragma unroll
                for (int j = 0; j < 4; ++j)
                    acc[i][j] = __builtin_amdgcn_mfma_f32_16x16x32_bf16(af[i], bfr[j], acc[i][j], 0, 0, 0);
        }
    }
    #pragma unroll
    for (int i = 0; i < 4; ++i)
        #pragma unroll
        for (int j = 0; j < 4; ++j)
            #pragma unroll
            for (int r = 0; r < 4; ++r) {
                int m = m0 + wm * 64 + i * 16 + quad * 4 + r;
                int n = n0 + wn * 64 + j * 16 + lane16;
                C[(size_t)m * D_ + n] = acc[i][j][r];
            }
}

// ---------------------------------------------------------------------------
// MFMA flash attention, bf16 in/out. q supplied as hi+lo bf16 pair
// (pre-scaled by 0.125), scores use 2-term q for fp32-grade q precision.
// Block = 4 waves, 64 queries. Layouts verified in R2.
// ---------------------------------------------------------------------------
__global__ __launch_bounds__(256) void attn_mfma(const ushort_t* __restrict__ qhib,
                                                 const ushort_t* __restrict__ qlob,
                                                 const ushort_t* __restrict__ kb,
                                                 const ushort_t* __restrict__ vb,
                                                 ushort_t* __restrict__ att) {
    __shared__ __align__(16) short Kl[64][72];
    __shared__ __align__(16) short Vt[64][72];
    __shared__ __align__(16) short Pl[4][16][80];

    const int bx = blockIdx.x;
    const int bh = bx >> 5;            // / (S/64)
    const int qt = bx & 31;
    const int qbase = qt * 64;
    const int t  = threadIdx.x;
    const int w  = t >> 6;
    const int ln = t & 63;
    const int lane16 = ln & 15;
    const int quad   = ln >> 4;
    const int b = bh >> 4, h = bh & 15;

    const ushort_t* qhg = qhib + (size_t)bh * S_ * HD_;
    const ushort_t* qlg = qlob + (size_t)bh * S_ * HD_;
    const ushort_t* kg  = kb   + (size_t)bh * S_ * HD_;
    const ushort_t* vg  = vb   + (size_t)bh * S_ * HD_;

    // Q fragments (A-layout), hi+lo
    bf16x8 aqh[2], aql[2];
    {
        size_t ro = (size_t)(qbase + w * 16 + lane16) * HD_;
        aqh[0] = *(const bf16x8*)(qhg + ro + quad * 8);
        aqh[1] = *(const bf16x8*)(qhg + ro + 32 + quad * 8);
        aql[0] = *(const bf16x8*)(qlg + ro + quad * 8);
        aql[1] = *(const bf16x8*)(qlg + ro + 32 + quad * 8);
    }

    float m_[4], l_[4];
    f32x4 Of[4];
    #pragma unroll
    for (int r = 0; r < 4; ++r) { m_[r] = -1e30f; l_[r] = 0.f; }
    #pragma unroll
    for (int nt = 0; nt < 4; ++nt) Of[nt] = (f32x4){0.f, 0.f, 0.f, 0.f};

    const int ntiles = qt + 1;
    for (int jt = 0; jt < ntiles; ++jt) {
        const int j0 = jt * 64;
        __syncthreads();
        {   // stage K tile: Kl[key][d]
            int r  = t >> 2;
            int c0 = (t & 3) * 16;
            const ushort_t* kr = kg + (size_t)(j0 + r) * HD_ + c0;
            bf16x8 p0 = *(const bf16x8*)(kr);
            bf16x8 p1 = *(const bf16x8*)(kr + 8);
            *(bf16x8*)&Kl[r][c0]     = p0;
            *(bf16x8*)&Kl[r][c0 + 8] = p1;
        }
        {   // stage V tile transposed: Vt[d][key]
            int r  = t & 63;
            int c0 = (t >> 6) * 16;
            const ushort_t* vr = vg + (size_t)(j0 + r) * HD_ + c0;
            bf16x8 v0 = *(const bf16x8*)(vr);
            bf16x8 v1 = *(const bf16x8*)(vr + 8);
            #pragma unroll
            for (int u = 0; u < 8; ++u) Vt[c0 + u][r] = v0[u];
            #pragma unroll
            for (int u = 0; u < 8; ++u) Vt[c0 + 8 + u][r] = v1[u];
        }
        __syncthreads();

        // scores: S[16 q][64 keys] per wave, 2-term q
        f32x4 Sf[4];
        #pragma unroll
        for (int nt = 0; nt < 4; ++nt) {
            bf16x8 bk0 = *(const bf16x8*)&Kl[nt * 16 + lane16][quad * 8];
            bf16x8 bk1 = *(const bf16x8*)&Kl[nt * 16 + lane16][32 + quad * 8];
            f32x4 z = (f32x4){0.f, 0.f, 0.f, 0.f};
            z = __builtin_amdgcn_mfma_f32_16x16x32_bf16(aqh[0], bk0, z, 0, 0, 0);
            z = __builtin_amdgcn_mfma_f32_16x16x32_bf16(aql[0], bk0, z, 0, 0, 0);
            z = __builtin_amdgcn_mfma_f32_16x16x32_bf16(aqh[1], bk1, z, 0, 0, 0);
            z = __builtin_amdgcn_mfma_f32_16x16x32_bf16(aql[1], bk1, z, 0, 0, 0);
            Sf[nt] = z;
        }

        if (jt == qt) {   // diagonal tile: causal mask
            #pragma unroll
            for (int nt = 0; nt < 4; ++nt)
                #pragma unroll
                for (int r = 0; r < 4; ++r) {
                    int key = j0 + nt * 16 + lane16;
                    int qq  = qbase + w * 16 + quad * 4 + r;
                    if (key > qq) Sf[nt][r] = -1e30f;
                }
        }

        // online softmax per query row
        float alpha[4];
        #pragma unroll
        for (int r = 0; r < 4; ++r) {
            float mx = fmaxf(fmaxf(Sf[0][r], Sf[1][r]), fmaxf(Sf[2][r], Sf[3][r]));
            #pragma unroll
            for (int off = 1; off < 16; off <<= 1) mx = fmaxf(mx, __shfl_xor(mx, off, 64));
            float mn = fmaxf(m_[r], mx);
            float p0 = __expf(Sf[0][r] - mn);
            float p1 = __expf(Sf[1][r] - mn);
            float p2 = __expf(Sf[2][r] - mn);
            float p3 = __expf(Sf[3][r] - mn);
            float ts = (p0 + p1) + (p2 + p3);
            #pragma unroll
            for (int off = 1; off < 16; off <<= 1) ts += __shfl_xor(ts, off, 64);
            alpha[r] = __expf(m_[r] - mn);
            l_[r] = l_[r] * alpha[r] + ts;
            m_[r] = mn;
            int row = quad * 4 + r;
            Pl[w][row][lane16]      = f2bf(p0);
            Pl[w][row][16 + lane16] = f2bf(p1);
            Pl[w][row][32 + lane16] = f2bf(p2);
            Pl[w][row][48 + lane16] = f2bf(p3);
        }

        // rescale O, then PV (wave-private Pl: no barrier needed)
        #pragma unroll
        for (int nt = 0; nt < 4; ++nt)
            #pragma unroll
            for (int r = 0; r < 4; ++r) Of[nt][r] *= alpha[r];

        #pragma unroll
        for (int kk = 0; kk < 2; ++kk) {
            bf16x8 ap = *(const bf16x8*)&Pl[w][lane16][kk * 32 + quad * 8];
            #pragma unroll
            for (int nt = 0; nt < 4; ++nt) {
                bf16x8 bv = *(const bf16x8*)&Vt[nt * 16 + lane16][kk * 32 + quad * 8];
                Of[nt] = __builtin_amdgcn_mfma_f32_16x16x32_bf16(ap, bv, Of[nt], 0, 0, 0);
            }
        }
    }

    // epilogue: att bf16 in [B,S,H*HD]
    #pragma unroll
    for (int r = 0; r < 4; ++r) {
        int s = qbase + w * 16 + quad * 4 + r;
        float inv_l = 1.0f / l_[r];
        ushort_t* dst = att + ((size_t)(b * S_ + s)) * D_ + h * HD_;
        #pragma unroll
        for (int nt = 0; nt < 4; ++nt)
            dst[nt * 16 + lane16] = (ushort_t)f2bf(Of[nt][r] * inv_l);
    }
}

// ---------------------------------------------------------------------------
extern "C" void kernel_launch(void* const* d_in, const int* in_sizes, int n_in,
                              void* d_out, int out_size, void* d_ws, size_t ws_size,
                              hipStream_t stream) {
    const float* X    = (const float*)d_in[0];   // [B,S,D] fp32
    const float* Wqkv = (const float*)d_in[2];   // [3D,D] fp32
    const float* Wo   = (const float*)d_in[3];   // [D,D] fp32
    float* out = (float*)d_out;

    ushort_t* ws = (ushort_t*)d_ws;
    const size_t QS = (size_t)B_ * H_ * S_ * HD_;   // 4,194,304 elems
    ushort_t* qhi  = ws;
    ushort_t* qlo  = ws + QS;
    ushort_t* kbuf = ws + 2 * QS;
    ushort_t* vbuf = ws + 3 * QS;
    ushort_t* attb = ws + 4 * QS;                   // [4096][1024]
    ushort_t* Wob  = ws + 5 * QS;                   // [1024][1024]

    cvt_bf16<<<512, 256, 0, stream>>>(Wo, Wob, (D_ * D_) / 8);
    gemm_qkv_split<<<dim3(NE_ / 128, M_ / 128), 256, 0, stream>>>(X, Wqkv, qhi, qlo, kbuf, vbuf);
    attn_mfma<<<B_ * H_ * (S_ / 64), 256, 0, stream>>>(qhi, qlo, kbuf, vbuf, attb);
    gemm_out_bf16<<<dim3(D_ / 128, M_ / 128), 256, 0, stream>>>(attb, Wob, out);
}

// Round 6
// 321.582 us; speedup vs baseline: 4.6003x; 1.3554x over previous
//
#include <hip/hip_runtime.h>
#include <hip/hip_bf16.h>
#include <math.h>

// Problem constants (fixed by setup_inputs)
#define B_  2
#define S_  2048
#define D_  1024
#define H_  16
#define HD_ 64
#define NE_ 3072   // 3*D
#define M_  4096   // B*S

typedef unsigned short ushort_t;
typedef __attribute__((ext_vector_type(8))) short bf16x8;
typedef __attribute__((ext_vector_type(4))) float f32x4;

__device__ __forceinline__ short f2bf(float f) {
    union { float f; unsigned u; } v; v.f = f;
    unsigned u = v.u;
    u += 0x7fffu + ((u >> 16) & 1u);   // round-to-nearest-even
    return (short)(u >> 16);
}
__device__ __forceinline__ float bf2f(short h) {
    union { unsigned u; float f; } v;
    v.u = ((unsigned)(unsigned short)h) << 16;
    return v.f;
}

// async global->LDS, 16B per lane; LDS dest = wave-uniform base + lane*16
__device__ __forceinline__ void async16(const ushort_t* g, ushort_t* l) {
    __builtin_amdgcn_global_load_lds(
        (const __attribute__((address_space(1))) void*)g,
        (__attribute__((address_space(3))) void*)l,
        16, 0, 0);
}

// ---------------------------------------------------------------------------
// fp32 -> bf16 (8 elems/thread) — Wo
// ---------------------------------------------------------------------------
__global__ __launch_bounds__(256) void cvt_bf16(const float* __restrict__ s,
                                                ushort_t* __restrict__ d, int n8) {
    int i = blockIdx.x * 256 + threadIdx.x;
    if (i >= n8) return;
    const float4* sp = (const float4*)s;
    float4 a = sp[2 * (size_t)i], b = sp[2 * (size_t)i + 1];
    bf16x8 o;
    o[0] = f2bf(a.x); o[1] = f2bf(a.y); o[2] = f2bf(a.z); o[3] = f2bf(a.w);
    o[4] = f2bf(b.x); o[5] = f2bf(b.y); o[6] = f2bf(b.z); o[7] = f2bf(b.w);
    *(bf16x8*)(d + 8 * (size_t)i) = o;
}

// fp32 -> bf16 hi+lo split (8 elems/thread). loRows8 = number of 8-elem
// groups for which lo is written (first 2048 rows of Wqkv; all of X).
__global__ __launch_bounds__(256) void split_bf16(const float* __restrict__ s,
                                                  ushort_t* __restrict__ dh,
                                                  ushort_t* __restrict__ dl,
                                                  int n8, int nlo8) {
    int i = blockIdx.x * 256 + threadIdx.x;
    if (i >= n8) return;
    const float4* sp = (const float4*)s;
    float4 a = sp[2 * (size_t)i], b = sp[2 * (size_t)i + 1];
    bf16x8 hi, lo;
    short h;
    h = f2bf(a.x); hi[0] = h; lo[0] = f2bf(a.x - bf2f(h));
    h = f2bf(a.y); hi[1] = h; lo[1] = f2bf(a.y - bf2f(h));
    h = f2bf(a.z); hi[2] = h; lo[2] = f2bf(a.z - bf2f(h));
    h = f2bf(a.w); hi[3] = h; lo[3] = f2bf(a.w - bf2f(h));
    h = f2bf(b.x); hi[4] = h; lo[4] = f2bf(b.x - bf2f(h));
    h = f2bf(b.y); hi[5] = h; lo[5] = f2bf(b.y - bf2f(h));
    h = f2bf(b.z); hi[6] = h; lo[6] = f2bf(b.z - bf2f(h));
    h = f2bf(b.w); hi[7] = h; lo[7] = f2bf(b.w - bf2f(h));
    *(bf16x8*)(dh + 8 * (size_t)i) = hi;
    if (i < nlo8) *(bf16x8*)(dl + 8 * (size_t)i) = lo;
}

// ---------------------------------------------------------------------------
// Split-precision QKV GEMM, m97 async structure, fused RoPE epilogue.
// Inputs pre-split to bf16 hi/lo in global. q,k blocks (n0<2048): 3-pass
// MFMA (xh*wh + xh*wl + xl*wh) = fp32-grade. v blocks: single-pass bf16.
// 128x128 tile, BK=64, XOR-swizzled LDS staged via global_load_lds w=16.
// Epilogue: RoPE via __shfl_xor; q scaled 0.125, stored bf16 hi+lo;
// k,v single bf16. Layout [B,H,S,HD].
// ---------------------------------------------------------------------------
__global__ __launch_bounds__(256) void gemm_qkv_split(const ushort_t* __restrict__ Xh,
                                                      const ushort_t* __restrict__ Xl,
                                                      const ushort_t* __restrict__ Wh,
                                                      const ushort_t* __restrict__ Wl,
                                                      ushort_t* __restrict__ qhi,
                                                      ushort_t* __restrict__ qlo,
                                                      ushort_t* __restrict__ kb,
                                                      ushort_t* __restrict__ vb) {
    __shared__ ushort_t Ah[128 * 64];
    __shared__ ushort_t Al[128 * 64];
    __shared__ ushort_t Bh[128 * 64];
    __shared__ ushort_t Bl[128 * 64];
    const int t = threadIdx.x;
    const int w = t >> 6, ln = t & 63;
    const int lane16 = ln & 15, quad = ln >> 4;
    const int wm = w >> 1, wn = w & 1;
    const int m0 = blockIdx.y * 128, n0 = blockIdx.x * 128;
    const int c = n0 >> 10;               // 0=q 1=k 2=v (uniform per block)
    const bool split = (c < 2);
    const int srow8 = ln >> 3;
    const int schunk = (ln & 7) ^ srow8;

    f32x4 acc[4][4];
    #pragma unroll
    for (int i = 0; i < 4; ++i)
        #pragma unroll
        for (int j = 0; j < 4; ++j) acc[i][j] = (f32x4){0.f, 0.f, 0.f, 0.f};

    for (int k0 = 0; k0 < D_; k0 += 64) {
        __syncthreads();
        #pragma unroll
        for (int i = 0; i < 4; ++i) {
            int rr = (i * 4 + w) * 8 + srow8;
            size_t offA = (size_t)(m0 + rr) * D_ + k0 + schunk * 8;
            size_t offB = (size_t)(n0 + rr) * D_ + k0 + schunk * 8;
            async16(Xh + offA, Ah + (i * 4 + w) * 512);
            async16(Wh + offB, Bh + (i * 4 + w) * 512);
            if (split) {
                async16(Xl + offA, Al + (i * 4 + w) * 512);
                async16(Wl + offB, Bl + (i * 4 + w) * 512);
            }
        }
        __syncthreads();
        #pragma unroll
        for (int kc = 0; kc < 2; ++kc) {
            bf16x8 ah[4], bh[4];
            #pragma unroll
            for (int i = 0; i < 4; ++i) {
                int ra = wm * 64 + i * 16 + lane16;
                int ca = (kc * 4 + quad) ^ (ra & 7);
                ah[i] = *(const bf16x8*)&Ah[ra * 64 + ca * 8];
                int rb = wn * 64 + i * 16 + lane16;
                int cb = (kc * 4 + quad) ^ (rb & 7);
                bh[i] = *(const bf16x8*)&Bh[rb * 64 + cb * 8];
            }
            #pragma unroll
            for (int i = 0; i < 4; ++i)
                #pragma unroll
                for (int j = 0; j < 4; ++j)
                    acc[i][j] = __builtin_amdgcn_mfma_f32_16x16x32_bf16(ah[i], bh[j], acc[i][j], 0, 0, 0);
            if (split) {
                bf16x8 al[4], bl[4];
                #pragma unroll
                for (int i = 0; i < 4; ++i) {
                    int ra = wm * 64 + i * 16 + lane16;
                    int ca = (kc * 4 + quad) ^ (ra & 7);
                    al[i] = *(const bf16x8*)&Al[ra * 64 + ca * 8];
                    int rb = wn * 64 + i * 16 + lane16;
                    int cb = (kc * 4 + quad) ^ (rb & 7);
                    bl[i] = *(const bf16x8*)&Bl[rb * 64 + cb * 8];
                }
                #pragma unroll
                for (int i = 0; i < 4; ++i)
                    #pragma unroll
                    for (int j = 0; j < 4; ++j) {
                        acc[i][j] = __builtin_amdgcn_mfma_f32_16x16x32_bf16(ah[i], bl[j], acc[i][j], 0, 0, 0);
                        acc[i][j] = __builtin_amdgcn_mfma_f32_16x16x32_bf16(al[i], bh[j], acc[i][j], 0, 0, 0);
                    }
            }
        }
    }

    // epilogue: fused RoPE (pair partner is adjacent lane), scatter to q/k/v
    const bool odd = (lane16 & 1) != 0;
    const int h = (n0 >> 6) & 15;
    #pragma unroll
    for (int j = 0; j < 4; ++j) {
        int nb = n0 + wn * 64 + j * 16;
        int hh_ = (nb >> 6) & 15;
        int dcol = (nb & 63) + lane16;   // 0..63
        int tt = dcol >> 1;
        float inv = exp2f(-(float)tt * (13.287712379549449f / 32.0f));
        #pragma unroll
        for (int i = 0; i < 4; ++i)
            #pragma unroll
            for (int r = 0; r < 4; ++r) {
                int m = m0 + wm * 64 + i * 16 + quad * 4 + r;
                int b = m >> 11, s = m & (S_ - 1);
                size_t idx = ((size_t)((b * H_ + hh_) * S_ + s)) * HD_ + dcol;
                float val = acc[i][j][r];
                if (c < 2) {
                    float part = __shfl_xor(val, 1, 64);
                    float ang = (float)s * inv;
                    float sn = __sinf(ang);
                    float cs = __cosf(ang);
                    float x1 = odd ? part : val;
                    float x2 = odd ? val : part;
                    float res = odd ? fmaf(x1, sn, x2 * cs) : fmaf(x1, cs, -x2 * sn);
                    if (c == 0) {
                        float vs = res * 0.125f;         // fold 1/sqrt(hd)
                        short hv = f2bf(vs);
                        qhi[idx] = (ushort_t)hv;
                        qlo[idx] = (ushort_t)f2bf(vs - bf2f(hv));
                    } else {
                        kb[idx] = (ushort_t)f2bf(res);
                    }
                } else {
                    vb[idx] = (ushort_t)f2bf(val);
                }
            }
    }
    (void)h;
}

// ---------------------------------------------------------------------------
// O-projection (single-pass bf16 MFMA, m97 structure): A=attb, W=Wob, C=out fp32
// ---------------------------------------------------------------------------
__global__ __launch_bounds__(256) void gemm_out_bf16(const ushort_t* __restrict__ Ag,
                                                     const ushort_t* __restrict__ Wg,
                                                     float* __restrict__ C) {
    __shared__ ushort_t As[128 * 64];
    __shared__ ushort_t Bs[128 * 64];
    const int t = threadIdx.x;
    const int w = t >> 6, ln = t & 63;
    const int lane16 = ln & 15, quad = ln >> 4;
    const int wm = w >> 1, wn = w & 1;
    const int m0 = blockIdx.y * 128, n0 = blockIdx.x * 128;
    const int srow8 = ln >> 3;
    const int schunk = (ln & 7) ^ srow8;
    f32x4 acc[4][4];
    #pragma unroll
    for (int i = 0; i < 4; ++i)
        #pragma unroll
        for (int j = 0; j < 4; ++j) acc[i][j] = (f32x4){0.f, 0.f, 0.f, 0.f};
    for (int k0 = 0; k0 < D_; k0 += 64) {
        __syncthreads();
        #pragma unroll
        for (int i = 0; i < 4; ++i) {
            int rr = (i * 4 + w) * 8 + srow8;
            async16(Ag + (size_t)(m0 + rr) * D_ + k0 + schunk * 8, As + (i * 4 + w) * 512);
            async16(Wg + (size_t)(n0 + rr) * D_ + k0 + schunk * 8, Bs + (i * 4 + w) * 512);
        }
        __syncthreads();
        #pragma unroll
        for (int kc = 0; kc < 2; ++kc) {
            bf16x8 af[4], bfr[4];
            #pragma unroll
            for (int i = 0; i < 4; ++i) {
                int ra = wm * 64 + i * 16 + lane16;
                int ca = (kc * 4 + quad) ^ (ra & 7);
                af[i] = *(const bf16x8*)&As[ra * 64 + ca * 8];
                int rb = wn * 64 + i * 16 + lane16;
                int cb = (kc * 4 + quad) ^ (rb & 7);
                bfr[i] = *(const bf16x8*)&Bs[rb * 64 + cb * 8];
            }
            #pragma unroll
            for (int i = 0; i < 4; ++i)
                #pragma unroll
                for (int j = 0; j < 4; ++j)
                    acc[i][j] = __builtin_amdgcn_mfma_f32_16x16x32_bf16(af[i], bfr[j], acc[i][j], 0, 0, 0);
        }
    }
    #pragma unroll
    for (int i = 0; i < 4; ++i)
        #pragma unroll
        for (int j = 0; j < 4; ++j)
            #pragma unroll
            for (int r = 0; r < 4; ++r) {
                int m = m0 + wm * 64 + i * 16 + quad * 4 + r;
                int n = n0 + wn * 64 + j * 16 + lane16;
                C[(size_t)m * D_ + n] = acc[i][j][r];
            }
}

// ---------------------------------------------------------------------------
// MFMA flash attention, bf16 in/out. q supplied as hi+lo bf16 pair
// (pre-scaled by 0.125), scores use 2-term q. Block = 4 waves, 64 queries.
// ---------------------------------------------------------------------------
__global__ __launch_bounds__(256) void attn_mfma(const ushort_t* __restrict__ qhib,
                                                 const ushort_t* __restrict__ qlob,
                                                 const ushort_t* __restrict__ kb,
                                                 const ushort_t* __restrict__ vb,
                                                 ushort_t* __restrict__ att) {
    __shared__ __align__(16) short Kl[64][72];
    __shared__ __align__(16) short Vt[64][72];
    __shared__ __align__(16) short Pl[4][16][80];

    const int bx = blockIdx.x;
    const int bh = bx >> 5;            // / (S/64)
    const int qt = bx & 31;
    const int qbase = qt * 64;
    const int t  = threadIdx.x;
    const int w  = t >> 6;
    const int ln = t & 63;
    const int lane16 = ln & 15;
    const int quad   = ln >> 4;
    const int b = bh >> 4, h = bh & 15;

    const ushort_t* qhg = qhib + (size_t)bh * S_ * HD_;
    const ushort_t* qlg = qlob + (size_t)bh * S_ * HD_;
    const ushort_t* kg  = kb   + (size_t)bh * S_ * HD_;
    const ushort_t* vg  = vb   + (size_t)bh * S_ * HD_;

    // Q fragments (A-layout), hi+lo
    bf16x8 aqh[2], aql[2];
    {
        size_t ro = (size_t)(qbase + w * 16 + lane16) * HD_;
        aqh[0] = *(const bf16x8*)(qhg + ro + quad * 8);
        aqh[1] = *(const bf16x8*)(qhg + ro + 32 + quad * 8);
        aql[0] = *(const bf16x8*)(qlg + ro + quad * 8);
        aql[1] = *(const bf16x8*)(qlg + ro + 32 + quad * 8);
    }

    float m_[4], l_[4];
    f32x4 Of[4];
    #pragma unroll
    for (int r = 0; r < 4; ++r) { m_[r] = -1e30f; l_[r] = 0.f; }
    #pragma unroll
    for (int nt = 0; nt < 4; ++nt) Of[nt] = (f32x4){0.f, 0.f, 0.f, 0.f};

    const int ntiles = qt + 1;
    for (int jt = 0; jt < ntiles; ++jt) {
        const int j0 = jt * 64;
        __syncthreads();
        {   // stage K tile: Kl[key][d]
            int r  = t >> 2;
            int c0 = (t & 3) * 16;
            const ushort_t* kr = kg + (size_t)(j0 + r) * HD_ + c0;
            bf16x8 p0 = *(const bf16x8*)(kr);
            bf16x8 p1 = *(const bf16x8*)(kr + 8);
            *(bf16x8*)&Kl[r][c0]     = p0;
            *(bf16x8*)&Kl[r][c0 + 8] = p1;
        }
        {   // stage V tile transposed: Vt[d][key]
            int r  = t & 63;
            int c0 = (t >> 6) * 16;
            const ushort_t* vr = vg + (size_t)(j0 + r) * HD_ + c0;
            bf16x8 v0 = *(const bf16x8*)(vr);
            bf16x8 v1 = *(const bf16x8*)(vr + 8);
            #pragma unroll
            for (int u = 0; u < 8; ++u) Vt[c0 + u][r] = v0[u];
            #pragma unroll
            for (int u = 0; u < 8; ++u) Vt[c0 + 8 + u][r] = v1[u];
        }
        __syncthreads();

        // scores: S[16 q][64 keys] per wave, 2-term q
        f32x4 Sf[4];
        #pragma unroll
        for (int nt = 0; nt < 4; ++nt) {
            bf16x8 bk0 = *(const bf16x8*)&Kl[nt * 16 + lane16][quad * 8];
            bf16x8 bk1 = *(const bf16x8*)&Kl[nt * 16 + lane16][32 + quad * 8];
            f32x4 z = (f32x4){0.f, 0.f, 0.f, 0.f};
            z = __builtin_amdgcn_mfma_f32_16x16x32_bf16(aqh[0], bk0, z, 0, 0, 0);
            z = __builtin_amdgcn_mfma_f32_16x16x32_bf16(aql[0], bk0, z, 0, 0, 0);
            z = __builtin_amdgcn_mfma_f32_16x16x32_bf16(aqh[1], bk1, z, 0, 0, 0);
            z = __builtin_amdgcn_mfma_f32_16x16x32_bf16(aql[1], bk1, z, 0, 0, 0);
            Sf[nt] = z;
        }

        if (jt == qt) {   // diagonal tile: causal mask
            #pragma unroll
            for (int nt = 0; nt < 4; ++nt)
                #pragma unroll
                for (int r = 0; r < 4; ++r) {
                    int key = j0 + nt * 16 + lane16;
                    int qq  = qbase + w * 16 + quad * 4 + r;
                    if (key > qq) Sf[nt][r] = -1e30f;
                }
        }

        // online softmax per query row
        float alpha[4];
        #pragma unroll
        for (int r = 0; r < 4; ++r) {
            float mx = fmaxf(fmaxf(Sf[0][r], Sf[1][r]), fmaxf(Sf[2][r], Sf[3][r]));
            #pragma unroll
            for (int off = 1; off < 16; off <<= 1) mx = fmaxf(mx, __shfl_xor(mx, off, 64));
            float mn = fmaxf(m_[r], mx);
            float p0 = __expf(Sf[0][r] - mn);
            float p1 = __expf(Sf[1][r] - mn);
            float p2 = __expf(Sf[2][r] - mn);
            float p3 = __expf(Sf[3][r] - mn);
            float ts = (p0 + p1) + (p2 + p3);
            #pragma unroll
            for (int off = 1; off < 16; off <<= 1) ts += __shfl_xor(ts, off, 64);
            alpha[r] = __expf(m_[r] - mn);
            l_[r] = l_[r] * alpha[r] + ts;
            m_[r] = mn;
            int row = quad * 4 + r;
            Pl[w][row][lane16]      = f2bf(p0);
            Pl[w][row][16 + lane16] = f2bf(p1);
            Pl[w][row][32 + lane16] = f2bf(p2);
            Pl[w][row][48 + lane16] = f2bf(p3);
        }

        // rescale O, then PV (wave-private Pl: no barrier needed)
        #pragma unroll
        for (int nt = 0; nt < 4; ++nt)
            #pragma unroll
            for (int r = 0; r < 4; ++r) Of[nt][r] *= alpha[r];

        #pragma unroll
        for (int kk = 0; kk < 2; ++kk) {
            bf16x8 ap = *(const bf16x8*)&Pl[w][lane16][kk * 32 + quad * 8];
            #pragma unroll
            for (int nt = 0; nt < 4; ++nt) {
                bf16x8 bv = *(const bf16x8*)&Vt[nt * 16 + lane16][kk * 32 + quad * 8];
                Of[nt] = __builtin_amdgcn_mfma_f32_16x16x32_bf16(ap, bv, Of[nt], 0, 0, 0);
            }
        }
    }

    // epilogue: att bf16 in [B,S,H*HD]
    #pragma unroll
    for (int r = 0; r < 4; ++r) {
        int s = qbase + w * 16 + quad * 4 + r;
        float inv_l = 1.0f / l_[r];
        ushort_t* dst = att + ((size_t)(b * S_ + s)) * D_ + h * HD_;
        #pragma unroll
        for (int nt = 0; nt < 4; ++nt)
            dst[nt * 16 + lane16] = (ushort_t)f2bf(Of[nt][r] * inv_l);
    }
}

// ---------------------------------------------------------------------------
extern "C" void kernel_launch(void* const* d_in, const int* in_sizes, int n_in,
                              void* d_out, int out_size, void* d_ws, size_t ws_size,
                              hipStream_t stream) {
    const float* X    = (const float*)d_in[0];   // [B,S,D] fp32
    const float* Wqkv = (const float*)d_in[2];   // [3D,D] fp32
    const float* Wo   = (const float*)d_in[3];   // [D,D] fp32
    float* out = (float*)d_out;

    ushort_t* ws = (ushort_t*)d_ws;
    const size_t QS = (size_t)B_ * H_ * S_ * HD_;   // 4,194,304 elems
    ushort_t* qhi  = ws;                            // QS
    ushort_t* qlo  = qhi  + QS;                     // QS
    ushort_t* kbuf = qlo  + QS;                     // QS
    ushort_t* vbuf = kbuf + QS;                     // QS
    ushort_t* Wob  = vbuf + QS;                     // 1M
    ushort_t* Xh   = Wob  + (size_t)D_ * D_;        // 4M  (attb aliases this)
    ushort_t* Xl   = Xh   + (size_t)M_ * D_;        // 4M
    ushort_t* Wh   = Xl   + (size_t)M_ * D_;        // 3M
    ushort_t* Wl   = Wh   + (size_t)NE_ * D_;       // 2M (q,k rows only)
    ushort_t* attb = Xh;                            // alias: Xh dead after gemm_qkv
    // total = 4*QS + 1M + 4M + 4M + 3M + 2M = ~31.5M elems = 60 MiB

    split_bf16<<<2048, 256, 0, stream>>>(X, Xh, Xl, (M_ * D_) / 8, (M_ * D_) / 8);
    split_bf16<<<1536, 256, 0, stream>>>(Wqkv, Wh, Wl, (NE_ * D_) / 8, (2048 * D_) / 8);
    cvt_bf16<<<512, 256, 0, stream>>>(Wo, Wob, (D_ * D_) / 8);

    gemm_qkv_split<<<dim3(NE_ / 128, M_ / 128), 256, 0, stream>>>(Xh, Xl, Wh, Wl,
                                                                  qhi, qlo, kbuf, vbuf);
    attn_mfma<<<B_ * H_ * (S_ / 64), 256, 0, stream>>>(qhi, qlo, kbuf, vbuf, attb);
    gemm_out_bf16<<<dim3(D_ / 128, M_ / 128), 256, 0, stream>>>(attb, Wob, out);
}